// Round 13
// baseline (298.416 us; speedup 1.0000x reference)
//
#include <hip/hip_runtime.h>
#include <hip/hip_bf16.h>
#include <stdint.h>

#define B_SZ   512
#define NINST  4
#define D_IN   1024
#define D_OUTD 1024
#define CCOMP  64
#define MRANK  256
#define KTOT   (CCOMP*MRANK)   // 16384

typedef __attribute__((ext_vector_type(4))) float  f32x4;
typedef __attribute__((ext_vector_type(8))) __bf16 bf16x8;
typedef __attribute__((ext_vector_type(4))) __bf16 bf16x4;

__device__ inline void gload_lds16(const __bf16* g, __bf16* l) {
  __builtin_amdgcn_global_load_lds(
      (const __attribute__((address_space(1))) void*)g,
      (__attribute__((address_space(3))) void*)l, 16, 0, 0);
}

// ---------------------------------------------------------------------------
// Prepass A: xbf[i][b][k] = bf16(x[b][i][k]).
// ---------------------------------------------------------------------------
__global__ __launch_bounds__(256)
void xcvt_kernel(const float* __restrict__ x, __bf16* __restrict__ xbf)
{
  const int total = (B_SZ*NINST*D_IN) / 4;
  for (int v = blockIdx.x*256 + threadIdx.x; v < total; v += gridDim.x*256) {
    const int k4 = v & 255;
    const int i  = (v >> 8) & 3;
    const int b  = v >> 10;
    f32x4 f = ((const f32x4*)x)[v];
    bf16x4 h; h[0]=(__bf16)f.x; h[1]=(__bf16)f.y; h[2]=(__bf16)f.z; h[3]=(__bf16)f.w;
    ((bf16x4*)xbf)[((size_t)i*B_SZ + b)*256 + k4] = h;
  }
}

// ---------------------------------------------------------------------------
// Prepass B: Abf[i][c*256+m][d] = bf16(A[i][c][d][m])  (n-major transpose).
// FIXED vs R12: write phase now covers exactly the 64-d subtile
// (was OOB to 128 rows -> NaN), T padded to 260 (520 B stride, 8B-aligned).
// ---------------------------------------------------------------------------
__global__ __launch_bounds__(256)
void atr_kernel(const float* __restrict__ A, __bf16* __restrict__ Abf)
{
  const int bid = blockIdx.x;
  const int ic  = bid >> 2;
  const int s4  = bid & 3;
  const int i   = ic >> 6;
  const int c   = ic & 63;
  const int tid = threadIdx.x;

  __shared__ __bf16 T[64][260];

  for (int sub = 0; sub < 4; ++sub) {
    const int d0 = s4*256 + sub*64;
    // read 64 d x 256 m fp32 (coalesced over m), cvt -> T[d][m]
#pragma unroll
    for (int it = 0; it < 16; ++it) {
      const int idx = it*256 + tid;
      const int d   = idx >> 6;
      const int m4  = idx & 63;
      f32x4 v = *(const f32x4*)(A + ((size_t)ic*D_IN + d0 + d)*MRANK + m4*4);
      bf16x4 h; h[0]=(__bf16)v.x; h[1]=(__bf16)v.y; h[2]=(__bf16)v.z; h[3]=(__bf16)v.w;
      *(bf16x4*)(&T[d][m4*4]) = h;
    }
    __syncthreads();
    // write 256 m-rows x 64 d: 8 d-chunks (dgu) x 8 bf16, m = it*32+(tid>>3)
#pragma unroll
    for (int it = 0; it < 8; ++it) {
      const int m   = it*32 + (tid >> 3);
      const int dgu = tid & 7;
      bf16x8 h;
#pragma unroll
      for (int j = 0; j < 8; ++j) h[j] = T[dgu*8 + j][m];
      *(bf16x8*)(Abf + ((size_t)i*KTOT + (size_t)c*MRANK + m)*D_IN + d0 + dgu*8) = h;
    }
    __syncthreads();
  }
}

// ---------------------------------------------------------------------------
// Phase 1 LITE: inner[i][b][n] = mask * sum_d xbf[i][b][d]*Abf[i][n][d].
// EXACT p2 skeleton, BOTH operands via global_load_lds (no scalar loads,
// no cvt, no ds_write in loop).  Tile 128(b) x 128(n), BK=64, 4 waves,
// 64 steps = 4 n-segs of 16, 64 KB LDS, 2 blocks/CU, grid 512 XCD-chunked.
// ---------------------------------------------------------------------------
__global__ __launch_bounds__(256, 2)
void p1_lite(const __bf16* __restrict__ xbf, const __bf16* __restrict__ Abf,
             const int* __restrict__ mask, __bf16* __restrict__ inner)
{
  const int bid = blockIdx.x;
  const int L   = (bid & 7) * 64 + (bid >> 3);
  const int bt  = L & 3;
  const int ntg = (L >> 2) & 31;
  const int i   = L >> 7;
  const int b0  = bt * 128;
  const int n0g = ntg * 512;       // 4 segs x 128 n

  const int tid  = threadIdx.x;
  const int lane = tid & 63;
  const int wid  = tid >> 6;
  const int wr   = wid >> 1;
  const int wc   = wid & 1;

  __shared__ __align__(16) char smem[65536];
  __bf16* Xs = (__bf16*)smem;             // [2][128][64]
  __bf16* As = (__bf16*)(smem + 32768);   // [2][128][64] n-major

  f32x4 acc[4][4];
#pragma unroll
  for (int a_ = 0; a_ < 4; ++a_)
#pragma unroll
    for (int b_ = 0; b_ < 4; ++b_)
      acc[a_][b_] = (f32x4){0.f, 0.f, 0.f, 0.f};

  const __bf16* xbase = xbf + ((size_t)i * B_SZ + b0) * D_IN;
  const __bf16* abase = Abf + ((size_t)i * KTOT + n0g) * D_IN;

  auto stageXs = [&](int buf, int kt) {
#pragma unroll
    for (int q = 0; q < 4; ++q) {
      const int ci  = wid*4 + q;
      const int row = ci*8 + (lane >> 3);
      const int kch = (lane & 7) ^ (row & 7);
      gload_lds16(xbase + (size_t)row * D_IN + (kt & 15)*64 + kch*8,
                  Xs + buf*8192 + ci*512);
    }
  };
  auto stageAs = [&](int buf, int kt) {
    const __bf16* ab = abase + (size_t)(kt >> 4) * 128 * D_IN;
#pragma unroll
    for (int q = 0; q < 4; ++q) {
      const int ci  = wid*4 + q;
      const int row = ci*8 + (lane >> 3);
      const int kch = (lane & 7) ^ (row & 7);
      gload_lds16(ab + (size_t)row * D_IN + (kt & 15)*64 + kch*8,
                  As + buf*8192 + ci*512);
    }
  };
  auto computeStep = [&](int cur) {
#pragma unroll
    for (int kk = 0; kk < 2; ++kk) {
      const int oct = kk*4 + (lane >> 4);
      bf16x8 af[4];
#pragma unroll
      for (int mi = 0; mi < 4; ++mi) {
        const int row = wr*64 + mi*16 + (lane & 15);
        af[mi] = *(const bf16x8*)(Xs + cur*8192 + row*64 + ((oct ^ (row & 7)))*8);
      }
#pragma unroll
      for (int ni = 0; ni < 4; ++ni) {
        const int col = wc*64 + ni*16 + (lane & 15);
        bf16x8 bfr = *(const bf16x8*)(As + cur*8192 + col*64 + ((oct ^ (col & 7)))*8);
#pragma unroll
        for (int mi = 0; mi < 4; ++mi)
          acc[mi][ni] = __builtin_amdgcn_mfma_f32_16x16x32_bf16(af[mi], bfr, acc[mi][ni], 0, 0, 0);
      }
    }
  };
  auto segEpilogue = [&](int kt) {
    const int n0 = n0g + (kt >> 4) * 128;
    const int c  = n0 >> 8;
    __bf16* obase = inner + ((size_t)i * B_SZ + b0) * KTOT + n0;
    float mv[16];
#pragma unroll
    for (int mi = 0; mi < 4; ++mi)
#pragma unroll
      for (int j = 0; j < 4; ++j) {
        const int row = wr*64 + mi*16 + (lane >> 4)*4 + j;
        mv[mi*4+j] = (float)mask[(size_t)(b0 + row) * (NINST*CCOMP) + i*CCOMP + c];
      }
#pragma unroll
    for (int mi = 0; mi < 4; ++mi)
#pragma unroll
      for (int ni = 0; ni < 4; ++ni) {
        const int colL = wc*64 + ni*16 + (lane & 15);
#pragma unroll
        for (int j = 0; j < 4; ++j) {
          const int rowL = wr*64 + mi*16 + (lane >> 4)*4 + j;
          obase[(size_t)rowL * KTOT + colL] = (__bf16)(acc[mi][ni][j] * mv[mi*4+j]);
        }
#pragma unroll
        for (int j = 0; j < 4; ++j) acc[mi][ni][j] = 0.f;
      }
  };

  stageXs(0, 0); stageAs(0, 0);
  __syncthreads();

  int cur = 0;
  for (int kt = 0; kt < 64; ++kt) {
    if (kt+1 < 64) { stageXs(cur ^ 1, kt+1); stageAs(cur ^ 1, kt+1); }
    computeStep(cur);
    if ((kt & 15) == 15) segEpilogue(kt);
    __syncthreads();
    cur ^= 1;
  }
}

// ---------------------------------------------------------------------------
// Phase 1 FALLBACK (R9 exact, used when ws too small for Abf).
// ---------------------------------------------------------------------------
__global__ __launch_bounds__(256, 2)
void p1_fallback(const __bf16* __restrict__ xbf, const float* __restrict__ A,
                 const int* __restrict__ mask, __bf16* __restrict__ inner)
{
  const int bid = blockIdx.x;
  const int L   = (bid & 7) * 64 + (bid >> 3);
  const int bt  = L & 3;
  const int mt  = (L >> 2) & 1;
  const int icg = L >> 3;
  const int ic0 = icg * 4;
  const int i   = ic0 >> 6;
  const int c0  = ic0 & 63;
  const int b0  = bt * 128;
  const int m0  = mt * 128;

  const int tid  = threadIdx.x;
  const int lane = tid & 63;
  const int wid  = tid >> 6;
  const int wr   = wid >> 1;
  const int wc   = wid & 1;

  __shared__ __align__(16) char smem[65536];
  __bf16* Xs = (__bf16*)smem;
  __bf16* As = (__bf16*)(smem + 32768);

  f32x4 acc[4][4];
#pragma unroll
  for (int a_ = 0; a_ < 4; ++a_)
#pragma unroll
    for (int b_ = 0; b_ < 4; ++b_)
      acc[a_][b_] = (f32x4){0.f, 0.f, 0.f, 0.f};

  const __bf16* xbase  = xbf + ((size_t)i * B_SZ + b0) * D_IN;
  const float*  Abase0 = A + (size_t)ic0 * D_IN * MRANK + m0;

  const int bo = tid & 127;
  const int bg = tid >> 7;
  float areg[4][8];

  auto stageXs = [&](int buf, int kt) {
#pragma unroll
    for (int q = 0; q < 4; ++q) {
      const int ci  = wid*4 + q;
      const int row = ci*8 + (lane >> 3);
      const int kch = (lane & 7) ^ (row & 7);
      gload_lds16(xbase + (size_t)row * D_IN + (kt & 15)*64 + kch*8,
                  Xs + buf*8192 + ci*512);
    }
  };
  auto loadA = [&](int kt) {
    const float* Ab = Abase0 + (size_t)(kt >> 4) * D_IN * MRANK;
#pragma unroll
    for (int q = 0; q < 4; ++q)
#pragma unroll
      for (int j = 0; j < 8; ++j)
        areg[q][j] = Ab[(size_t)((kt & 15)*64 + (bg*4+q)*8 + j)*MRANK + bo];
  };
  auto writeA = [&](int buf) {
#pragma unroll
    for (int q = 0; q < 4; ++q) {
      const int oct = bg*4 + q;
      bf16x8 h;
#pragma unroll
      for (int j = 0; j < 8; ++j) h[j] = (__bf16)areg[q][j];
      *(bf16x8*)(As + buf*8192 + bo*64 + ((oct ^ (bo & 7)))*8) = h;
    }
  };

  stageXs(0, 0); loadA(0); writeA(0);
  __syncthreads();

  int cur = 0;
  for (int kt = 0; kt < 64; ++kt) {
    if (kt+1 < 64) { stageXs(cur ^ 1, kt+1); loadA(kt+1); }
#pragma unroll
    for (int kk = 0; kk < 2; ++kk) {
      const int oct = kk*4 + (lane >> 4);
      bf16x8 af[4];
#pragma unroll
      for (int mi = 0; mi < 4; ++mi) {
        const int row = wr*64 + mi*16 + (lane & 15);
        af[mi] = *(const bf16x8*)(Xs + cur*8192 + row*64 + ((oct ^ (row & 7)))*8);
      }
#pragma unroll
      for (int ni = 0; ni < 4; ++ni) {
        const int col = wc*64 + ni*16 + (lane & 15);
        bf16x8 bfr = *(const bf16x8*)(As + cur*8192 + col*64 + ((oct ^ (col & 7)))*8);
#pragma unroll
        for (int mi = 0; mi < 4; ++mi)
          acc[mi][ni] = __builtin_amdgcn_mfma_f32_16x16x32_bf16(af[mi], bfr, acc[mi][ni], 0, 0, 0);
      }
    }
    if ((kt & 15) == 15) {
      const int c = c0 + (kt >> 4);
      __bf16* obase = inner + ((size_t)i * B_SZ + b0) * KTOT + (size_t)c * MRANK + m0;
      float mv[16];
#pragma unroll
      for (int mi = 0; mi < 4; ++mi)
#pragma unroll
        for (int j = 0; j < 4; ++j) {
          const int row = wr*64 + mi*16 + (lane >> 4)*4 + j;
          mv[mi*4+j] = (float)mask[(size_t)(b0 + row) * (NINST*CCOMP) + i*CCOMP + c];
        }
#pragma unroll
      for (int mi = 0; mi < 4; ++mi)
#pragma unroll
        for (int ni = 0; ni < 4; ++ni) {
          const int colL = wc*64 + ni*16 + (lane & 15);
#pragma unroll
          for (int j = 0; j < 4; ++j) {
            const int rowL = wr*64 + mi*16 + (lane >> 4)*4 + j;
            obase[(size_t)rowL * KTOT + colL] = (__bf16)(acc[mi][ni][j] * mv[mi*4+j]);
          }
#pragma unroll
          for (int j = 0; j < 4; ++j) acc[mi][ni][j] = 0.f;
        }
    }
    if (kt+1 < 64) writeA(cur ^ 1);
    __syncthreads();
    cur ^= 1;
  }
}

// ---------------------------------------------------------------------------
// Phase 2 (R9 exact): part[ks][b][i][o] = sum_{K slice} inner . Bflat.
// ---------------------------------------------------------------------------
__global__ __launch_bounds__(256, 2)
void p2_kernel(const __bf16* __restrict__ inner, const float* __restrict__ Bm,
               float* __restrict__ dst, int nks)
{
  const int bid = blockIdx.x;
  const int L   = (bid & 7) * (gridDim.x >> 3) + (bid >> 3);
  const int bt  = L & 3;
  const int nt  = (L >> 2) & 7;
  const int rest = L >> 5;
  const int ks  = rest % nks;
  const int i   = rest / nks;
  const int b0  = bt * 128;
  const int o0  = nt * 128;
  const int NSTEP = (KTOT/64) / nks;
  const int kb0   = ks * NSTEP;

  const int tid  = threadIdx.x;
  const int lane = tid & 63;
  const int wid  = tid >> 6;
  const int wr   = wid >> 1;
  const int wc   = wid & 1;

  __shared__ __align__(16) char smem[65536];
  __bf16* Is = (__bf16*)smem;
  __bf16* Bs = (__bf16*)(smem + 32768);

  f32x4 acc[4][4];
#pragma unroll
  for (int a_ = 0; a_ < 4; ++a_)
#pragma unroll
    for (int b_ = 0; b_ < 4; ++b_)
      acc[a_][b_] = (f32x4){0.f, 0.f, 0.f, 0.f};

  const __bf16* ibase = inner + ((size_t)i * B_SZ + b0) * KTOT;
  const float*  Bbase = Bm + (size_t)i * KTOT * D_OUTD + o0;

  const int bo = tid & 127;
  const int bg = tid >> 7;
  float breg[4][8];

  auto stageIs = [&](int buf, int kt) {
#pragma unroll
    for (int q = 0; q < 4; ++q) {
      const int ci  = wid*4 + q;
      const int row = ci*8 + (lane >> 3);
      const int kch = (lane & 7) ^ (row & 7);
      gload_lds16(ibase + (size_t)row * KTOT + kt*64 + kch*8,
                  Is + buf*8192 + ci*512);
    }
  };
  auto loadB = [&](int kt) {
#pragma unroll
    for (int q = 0; q < 4; ++q)
#pragma unroll
      for (int j = 0; j < 8; ++j)
        breg[q][j] = Bbase[(size_t)(kt*64 + (bg*4+q)*8 + j)*D_OUTD + bo];
  };
  auto writeB = [&](int buf) {
#pragma unroll
    for (int q = 0; q < 4; ++q) {
      const int oct = bg*4 + q;
      bf16x8 h;
#pragma unroll
      for (int j = 0; j < 8; ++j) h[j] = (__bf16)breg[q][j];
      *(bf16x8*)(Bs + buf*8192 + bo*64 + ((oct ^ (bo & 7)))*8) = h;
    }
  };

  stageIs(0, kb0); loadB(kb0); writeB(0);
  __syncthreads();

  int cur = 0;
  for (int t = 0; t < NSTEP; ++t) {
    if (t+1 < NSTEP) { stageIs(cur ^ 1, kb0 + t + 1); loadB(kb0 + t + 1); }
#pragma unroll
    for (int kk = 0; kk < 2; ++kk) {
      const int oct = kk*4 + (lane >> 4);
      bf16x8 af[4];
#pragma unroll
      for (int mi = 0; mi < 4; ++mi) {
        const int row = wr*64 + mi*16 + (lane & 15);
        af[mi] = *(const bf16x8*)(Is + cur*8192 + row*64 + ((oct ^ (row & 7)))*8);
      }
#pragma unroll
      for (int ni = 0; ni < 4; ++ni) {
        const int col = wc*64 + ni*16 + (lane & 15);
        bf16x8 bfr = *(const bf16x8*)(Bs + cur*8192 + col*64 + ((oct ^ (col & 7)))*8);
#pragma unroll
        for (int mi = 0; mi < 4; ++mi)
          acc[mi][ni] = __builtin_amdgcn_mfma_f32_16x16x32_bf16(af[mi], bfr, acc[mi][ni], 0, 0, 0);
      }
    }
    if (t+1 < NSTEP) writeB(cur ^ 1);
    __syncthreads();
    cur ^= 1;
  }

  float* obase = dst + (size_t)ks * ((size_t)B_SZ*NINST*D_OUTD)
               + ((size_t)b0 * NINST + i) * D_OUTD + o0;
#pragma unroll
  for (int mi = 0; mi < 4; ++mi)
#pragma unroll
    for (int ni = 0; ni < 4; ++ni) {
      const int colL = wc*64 + ni*16 + (lane & 15);
#pragma unroll
      for (int j = 0; j < 4; ++j) {
        const int rowL = wr*64 + mi*16 + (lane >> 4)*4 + j;
        obase[(size_t)rowL * (NINST*D_OUTD) + colL] = acc[mi][ni][j];
      }
    }
}

__global__ __launch_bounds__(256)
void reduce_kernel(const float* __restrict__ part, float* __restrict__ out, int nks)
{
  const int total = (B_SZ*NINST*D_OUTD) / 4;
  for (int v = blockIdx.x*256 + threadIdx.x; v < total; v += gridDim.x*256) {
    f32x4 s = ((const f32x4*)part)[v];
    for (int ks = 1; ks < nks; ++ks)
      s += ((const f32x4*)part)[(size_t)ks*total + v];
    ((f32x4*)out)[v] = s;
  }
}

extern "C" void kernel_launch(void* const* d_in, const int* in_sizes, int n_in,
                              void* d_out, int out_size, void* d_ws, size_t ws_size,
                              hipStream_t stream) {
  const float* x    = (const float*)d_in[0];
  const float* A    = (const float*)d_in[1];
  const float* Bm   = (const float*)d_in[2];
  const int*   mask = (const int*)d_in[3];

  const size_t innerB = (size_t)NINST * B_SZ * KTOT * 2;       // 64 MB
  const size_t xbfB   = (size_t)NINST * B_SZ * D_IN * 2;       // 4 MB
  const size_t AbfB   = (size_t)NINST * KTOT * D_IN * 2;       // 128 MB
  const size_t partB  = (size_t)B_SZ * NINST * D_OUTD * 4;     // 8 MB

  char* p = (char*)d_ws;
  __bf16* inner = (__bf16*)p;             p += innerB;
  __bf16* xbf   = (__bf16*)p;             p += xbfB;

  const bool lite = (ws_size >= innerB + xbfB + AbfB);

  xcvt_kernel<<<dim3(1024), dim3(256), 0, stream>>>(x, xbf);

  int nks = 1;
  float* part;
  if (lite) {
    __bf16* Abf = (__bf16*)p;                 // 128 MB; parts overlay it later
    nks = 4;
    part = (float*)p;                          // p2 runs after p1 -> Abf dead
    atr_kernel<<<dim3(1024), dim3(256), 0, stream>>>(A, Abf);
    p1_lite<<<dim3(512), dim3(256), 0, stream>>>(xbf, Abf, mask, inner);
  } else {
    if      (ws_size >= innerB + xbfB + 4*partB) nks = 4;
    else if (ws_size >= innerB + xbfB + 2*partB) nks = 2;
    part = (nks > 1) ? (float*)p : (float*)d_out;
    p1_fallback<<<dim3(512), dim3(256), 0, stream>>>(xbf, A, mask, inner);
  }

  p2_kernel<<<dim3(128*nks), dim3(256), 0, stream>>>(inner, Bm, part, nks);
  if (nks > 1)
    reduce_kernel<<<dim3(512), dim3(256), 0, stream>>>(part, (float*)d_out, nks);
}

// Round 14
// 283.853 us; speedup vs baseline: 1.0513x; 1.0513x over previous
//
#include <hip/hip_runtime.h>
#include <hip/hip_bf16.h>
#include <stdint.h>

#define B_SZ   512
#define NINST  4
#define D_IN   1024
#define D_OUTD 1024
#define CCOMP  64
#define MRANK  256
#define KTOT   (CCOMP*MRANK)   // 16384

typedef __attribute__((ext_vector_type(4))) float  f32x4;
typedef __attribute__((ext_vector_type(8))) __bf16 bf16x8;
typedef __attribute__((ext_vector_type(4))) __bf16 bf16x4;

__device__ inline void gload16(const void* g, void* l) {
  __builtin_amdgcn_global_load_lds(
      (const __attribute__((address_space(1))) void*)g,
      (__attribute__((address_space(3))) void*)l, 16, 0, 0);
}

// Raw barriers (T4). BAR_V4 keeps the newest 4 VMEM ops (the 2-ahead A-DMA)
// in flight across the barrier; everything older (X-DMA, prior A-DMA,
// epilogue stores) is drained exactly when its consumer needs it.
#define BAR_LG() do { \
  asm volatile("s_waitcnt lgkmcnt(0)" ::: "memory"); \
  __builtin_amdgcn_sched_barrier(0); \
  __builtin_amdgcn_s_barrier(); \
  __builtin_amdgcn_sched_barrier(0); } while (0)
#define BAR_V4() do { \
  asm volatile("s_waitcnt lgkmcnt(0) vmcnt(4)" ::: "memory"); \
  __builtin_amdgcn_sched_barrier(0); \
  __builtin_amdgcn_s_barrier(); \
  __builtin_amdgcn_sched_barrier(0); } while (0)
#define BAR_V0() do { \
  asm volatile("s_waitcnt lgkmcnt(0) vmcnt(0)" ::: "memory"); \
  __builtin_amdgcn_sched_barrier(0); \
  __builtin_amdgcn_s_barrier(); \
  __builtin_amdgcn_sched_barrier(0); } while (0)

// ---------------------------------------------------------------------------
// Prepass: xbf[i][b][k] = bf16(x[b][i][k]).
// ---------------------------------------------------------------------------
__global__ __launch_bounds__(256)
void xcvt_kernel(const float* __restrict__ x, __bf16* __restrict__ xbf)
{
  const int total = (B_SZ*NINST*D_IN) / 4;
  for (int v = blockIdx.x*256 + threadIdx.x; v < total; v += gridDim.x*256) {
    const int k4 = v & 255;
    const int i  = (v >> 8) & 3;
    const int b  = v >> 10;
    f32x4 f = ((const f32x4*)x)[v];
    bf16x4 h; h[0]=(__bf16)f.x; h[1]=(__bf16)f.y; h[2]=(__bf16)f.z; h[3]=(__bf16)f.w;
    ((bf16x4*)xbf)[((size_t)i*B_SZ + b)*256 + k4] = h;
  }
}

// ---------------------------------------------------------------------------
// Phase 1: inner = mask * (x . A) with IN-KERNEL A transpose.
// Tile 128(b) x 128(m), BK=64, 512 thr = 8 waves (4x2), 64 steps (4 c-segs).
// A staged fp32 via global_load_lds (natural layout, 2-step-ahead, 3 bufs);
// per-step cvt pass: 16 scalar column LDS reads (conflict-free) -> bf16
// k-major LDS (proven swizzle).  X via DMA (2 bufs, 1-ahead).  bfA single
// buffer (2-barrier cycle serializes write/read/write).  LDS 144 KB, 1
// block/CU, counted-vmcnt barriers keep the A prefetch alive (T4).
// grid 512 XCD-chunked (2 rounds/CU).
// ---------------------------------------------------------------------------
__global__ __launch_bounds__(512, 1)
void p1_kernel(const __bf16* __restrict__ xbf, const float* __restrict__ A,
               const int* __restrict__ mask, __bf16* __restrict__ inner)
{
  const int bid = blockIdx.x;
  const int L   = (bid & 7) * 64 + (bid >> 3);   // XCD-chunked
  const int bt  = L & 3;
  const int mt  = (L >> 2) & 1;
  const int icg = L >> 3;          // 0..63
  const int ic0 = icg * 4;         // 4 consecutive c, same i
  const int i   = ic0 >> 6;
  const int c0  = ic0 & 63;
  const int b0  = bt * 128;
  const int m0  = mt * 128;

  const int tid  = threadIdx.x;
  const int lane = tid & 63;
  const int wid  = tid >> 6;       // 0..7
  const int wr   = wid & 3;        // 0..3 : 32-row strip
  const int wc   = wid >> 2;       // 0..1 : 64-col strip

  // Xs [2][128][64] bf16 @0 (32 KB); fA [3][64][128] fp32 @32768 (96 KB);
  // bfA [128][64] bf16 @131072 (16 KB).  Total 147456 B.
  __shared__ __align__(16) char smem[147456];
  __bf16* Xs  = (__bf16*)smem;
  float*  fA  = (float*)(smem + 32768);
  __bf16* bfA = (__bf16*)(smem + 131072);

  f32x4 acc[2][4];
#pragma unroll
  for (int a_ = 0; a_ < 2; ++a_)
#pragma unroll
    for (int b_ = 0; b_ < 4; ++b_)
      acc[a_][b_] = (f32x4){0.f, 0.f, 0.f, 0.f};

  const __bf16* xbase  = xbf + ((size_t)i * B_SZ + b0) * D_IN;
  const float*  Abase0 = A + (size_t)ic0 * D_IN * MRANK + m0;

  const int bo = tid & 127;        // m column for cvt
  const int bg = tid >> 7;         // 0..3 -> octet pair

  auto stageX = [&](int buf, int kt) {
#pragma unroll
    for (int q = 0; q < 2; ++q) {
      const int u   = wid*2 + q;                 // 0..15, wave-uniform
      const int row = u*8 + (lane >> 3);
      const int kch = (lane & 7) ^ (row & 7);
      gload16(xbase + (size_t)row * D_IN + (kt & 15)*64 + kch*8,
              Xs + buf*8192 + u*512);
    }
  };
  auto stageA32 = [&](int slot, int kt) {
    const float* Ab = Abase0 + (size_t)(kt >> 4) * D_IN * MRANK;
#pragma unroll
    for (int q = 0; q < 4; ++q) {
      const int u = wid*4 + q;                   // 0..31, wave-uniform
      const int d = u*2 + (lane >> 5);
      gload16(Ab + (size_t)((kt & 15)*64 + d) * MRANK + (lane & 31)*4,
              fA + slot*8192 + u*256);
    }
  };
  auto cvtA = [&](int slot) {
#pragma unroll
    for (int q = 0; q < 2; ++q) {
      const int oct = bg*2 + q;                  // 0..7
      bf16x8 h;
#pragma unroll
      for (int j = 0; j < 8; ++j)
        h[j] = (__bf16)fA[slot*8192 + (oct*8 + j)*128 + bo];  // column read
      *(bf16x8*)(bfA + bo*64 + ((oct ^ (bo & 7)))*8) = h;
    }
  };
  auto computeStep = [&](int xbuf) {
#pragma unroll
    for (int kk = 0; kk < 2; ++kk) {
      const int oct = kk*4 + (lane >> 4);
      bf16x8 af[2];
#pragma unroll
      for (int mi = 0; mi < 2; ++mi) {
        const int row = wr*32 + mi*16 + (lane & 15);
        af[mi] = *(const bf16x8*)(Xs + xbuf*8192 + row*64 + ((oct ^ (row & 7)))*8);
      }
#pragma unroll
      for (int ni = 0; ni < 4; ++ni) {
        const int col = wc*64 + ni*16 + (lane & 15);
        bf16x8 bfr = *(const bf16x8*)(bfA + col*64 + ((oct ^ (col & 7)))*8);
#pragma unroll
        for (int mi = 0; mi < 2; ++mi)
          acc[mi][ni] = __builtin_amdgcn_mfma_f32_16x16x32_bf16(af[mi], bfr, acc[mi][ni], 0, 0, 0);
      }
    }
  };
  auto segEpilogue = [&](int kt) {
    const int c = c0 + (kt >> 4);
    __bf16* obase = inner + ((size_t)i * B_SZ + b0) * KTOT + (size_t)c * MRANK + m0;
    float mv[8];
#pragma unroll
    for (int mi = 0; mi < 2; ++mi)
#pragma unroll
      for (int j = 0; j < 4; ++j) {
        const int row = wr*32 + mi*16 + (lane >> 4)*4 + j;
        mv[mi*4+j] = (float)mask[(size_t)(b0 + row) * (NINST*CCOMP) + i*CCOMP + c];
      }
#pragma unroll
    for (int mi = 0; mi < 2; ++mi)
#pragma unroll
      for (int ni = 0; ni < 4; ++ni) {
        const int colL = wc*64 + ni*16 + (lane & 15);
#pragma unroll
        for (int j = 0; j < 4; ++j) {
          const int rowL = wr*32 + mi*16 + (lane >> 4)*4 + j;
          obase[(size_t)rowL * KTOT + colL] = (__bf16)(acc[mi][ni][j] * mv[mi*4+j]);
        }
#pragma unroll
        for (int j = 0; j < 4; ++j) acc[mi][ni][j] = 0.f;
      }
  };

  // prologue: X(0) oldest, A(0), A(1) newest; keep A(1) in flight.
  stageX(0, 0);
  stageA32(0, 0);
  stageA32(1, 1);
  BAR_V4();

  for (int t = 0; t < 64; ++t) {
    if (t+1 < 64) stageX((t+1) & 1, t+1);   // in flight across whole step
    cvtA(t % 3);
    BAR_LG();                               // bfA visible to all
    computeStep(t & 1);
    if ((t & 15) == 15) segEpilogue(t);
    if (t+2 < 64) stageA32((t+2) % 3, t+2); // newest 4 vmem ops
    if (t < 63) { if (t < 62) BAR_V4(); else BAR_V0(); }
  }
}

// ---------------------------------------------------------------------------
// Phase 2 (R9 exact, measured ~92 us): part[ks] = sum_{K slice} inner . Bflat.
// ---------------------------------------------------------------------------
__global__ __launch_bounds__(256, 2)
void p2_kernel(const __bf16* __restrict__ inner, const float* __restrict__ Bm,
               float* __restrict__ dst, int nks)
{
  const int bid = blockIdx.x;
  const int L   = (bid & 7) * (gridDim.x >> 3) + (bid >> 3);
  const int bt  = L & 3;
  const int nt  = (L >> 2) & 7;
  const int rest = L >> 5;
  const int ks  = rest % nks;
  const int i   = rest / nks;
  const int b0  = bt * 128;
  const int o0  = nt * 128;
  const int NSTEP = (KTOT/64) / nks;
  const int kb0   = ks * NSTEP;

  const int tid  = threadIdx.x;
  const int lane = tid & 63;
  const int wid  = tid >> 6;
  const int wr   = wid >> 1;
  const int wc   = wid & 1;

  __shared__ __align__(16) char smem[65536];
  __bf16* Is = (__bf16*)smem;
  __bf16* Bs = (__bf16*)(smem + 32768);

  f32x4 acc[4][4];
#pragma unroll
  for (int a_ = 0; a_ < 4; ++a_)
#pragma unroll
    for (int b_ = 0; b_ < 4; ++b_)
      acc[a_][b_] = (f32x4){0.f, 0.f, 0.f, 0.f};

  const __bf16* ibase = inner + ((size_t)i * B_SZ + b0) * KTOT;
  const float*  Bbase = Bm + (size_t)i * KTOT * D_OUTD + o0;

  const int bo = tid & 127;
  const int bg = tid >> 7;
  float breg[4][8];

  auto stageIs = [&](int buf, int kt) {
#pragma unroll
    for (int q = 0; q < 4; ++q) {
      const int ci  = wid*4 + q;
      const int row = ci*8 + (lane >> 3);
      const int kch = (lane & 7) ^ (row & 7);
      gload16(ibase + (size_t)row * KTOT + kt*64 + kch*8,
              Is + buf*8192 + ci*512);
    }
  };
  auto loadB = [&](int kt) {
#pragma unroll
    for (int q = 0; q < 4; ++q)
#pragma unroll
      for (int j = 0; j < 8; ++j)
        breg[q][j] = Bbase[(size_t)(kt*64 + (bg*4+q)*8 + j)*D_OUTD + bo];
  };
  auto writeB = [&](int buf) {
#pragma unroll
    for (int q = 0; q < 4; ++q) {
      const int oct = bg*4 + q;
      bf16x8 h;
#pragma unroll
      for (int j = 0; j < 8; ++j) h[j] = (__bf16)breg[q][j];
      *(bf16x8*)(Bs + buf*8192 + bo*64 + ((oct ^ (bo & 7)))*8) = h;
    }
  };

  stageIs(0, kb0); loadB(kb0); writeB(0);
  __syncthreads();

  int cur = 0;
  for (int t = 0; t < NSTEP; ++t) {
    if (t+1 < NSTEP) { stageIs(cur ^ 1, kb0 + t + 1); loadB(kb0 + t + 1); }
#pragma unroll
    for (int kk = 0; kk < 2; ++kk) {
      const int oct = kk*4 + (lane >> 4);
      bf16x8 af[4];
#pragma unroll
      for (int mi = 0; mi < 4; ++mi) {
        const int row = wr*64 + mi*16 + (lane & 15);
        af[mi] = *(const bf16x8*)(Is + cur*8192 + row*64 + ((oct ^ (row & 7)))*8);
      }
#pragma unroll
      for (int ni = 0; ni < 4; ++ni) {
        const int col = wc*64 + ni*16 + (lane & 15);
        bf16x8 bfr = *(const bf16x8*)(Bs + cur*8192 + col*64 + ((oct ^ (col & 7)))*8);
#pragma unroll
        for (int mi = 0; mi < 4; ++mi)
          acc[mi][ni] = __builtin_amdgcn_mfma_f32_16x16x32_bf16(af[mi], bfr, acc[mi][ni], 0, 0, 0);
      }
    }
    if (t+1 < NSTEP) writeB(cur ^ 1);
    __syncthreads();
    cur ^= 1;
  }

  float* obase = dst + (size_t)ks * ((size_t)B_SZ*NINST*D_OUTD)
               + ((size_t)b0 * NINST + i) * D_OUTD + o0;
#pragma unroll
  for (int mi = 0; mi < 4; ++mi)
#pragma unroll
    for (int ni = 0; ni < 4; ++ni) {
      const int colL = wc*64 + ni*16 + (lane & 15);
#pragma unroll
      for (int j = 0; j < 4; ++j) {
        const int rowL = wr*64 + mi*16 + (lane >> 4)*4 + j;
        obase[(size_t)rowL * (NINST*D_OUTD) + colL] = acc[mi][ni][j];
      }
    }
}

__global__ __launch_bounds__(256)
void reduce_kernel(const float* __restrict__ part, float* __restrict__ out, int nks)
{
  const int total = (B_SZ*NINST*D_OUTD) / 4;
  for (int v = blockIdx.x*256 + threadIdx.x; v < total; v += gridDim.x*256) {
    f32x4 s = ((const f32x4*)part)[v];
    for (int ks = 1; ks < nks; ++ks)
      s += ((const f32x4*)part)[(size_t)ks*total + v];
    ((f32x4*)out)[v] = s;
  }
}

extern "C" void kernel_launch(void* const* d_in, const int* in_sizes, int n_in,
                              void* d_out, int out_size, void* d_ws, size_t ws_size,
                              hipStream_t stream) {
  const float* x    = (const float*)d_in[0];
  const float* A    = (const float*)d_in[1];
  const float* Bm   = (const float*)d_in[2];
  const int*   mask = (const int*)d_in[3];

  const size_t innerB = (size_t)NINST * B_SZ * KTOT * 2;       // 64 MB
  const size_t xbfB   = (size_t)NINST * B_SZ * D_IN * 2;       // 4 MB
  const size_t partB  = (size_t)B_SZ * NINST * D_OUTD * 4;     // 8 MB per split

  char* p = (char*)d_ws;
  __bf16* inner = (__bf16*)p;             p += innerB;
  __bf16* xbf   = (__bf16*)p;             p += xbfB;
  const size_t used = (size_t)(p - (char*)d_ws);

  int nks = 1;
  if      (ws_size >= used + 4*partB) nks = 4;
  else if (ws_size >= used + 2*partB) nks = 2;
  float* part = (nks > 1) ? (float*)p : (float*)d_out;

  xcvt_kernel<<<dim3(1024),  dim3(256), 0, stream>>>(x, xbf);
  p1_kernel<<<dim3(512),     dim3(512), 0, stream>>>(xbf, A, mask, inner);
  p2_kernel<<<dim3(128*nks), dim3(256), 0, stream>>>(inner, Bm, part, nks);
  if (nks > 1)
    reduce_kernel<<<dim3(512), dim3(256), 0, stream>>>(part, (float*)d_out, nks);
}

// Round 15
// 259.153 us; speedup vs baseline: 1.1515x; 1.0953x over previous
//
#include <hip/hip_runtime.h>
#include <hip/hip_bf16.h>
#include <stdint.h>

#define B_SZ   512
#define NINST  4
#define D_IN   1024
#define D_OUTD 1024
#define CCOMP  64
#define MRANK  256
#define KTOT   (CCOMP*MRANK)   // 16384

typedef __attribute__((ext_vector_type(4))) float  f32x4;
typedef __attribute__((ext_vector_type(8))) __bf16 bf16x8;
typedef __attribute__((ext_vector_type(4))) __bf16 bf16x4;

__device__ inline void gload16(const void* g, void* l) {
  __builtin_amdgcn_global_load_lds(
      (const __attribute__((address_space(1))) void*)g,
      (__attribute__((address_space(3))) void*)l, 16, 0, 0);
}

// Counted-vmcnt barrier (T4): keep the newest N VMEM ops in flight.
#define BARN(N) do { \
  asm volatile("s_waitcnt lgkmcnt(0) vmcnt(" #N ")" ::: "memory"); \
  __builtin_amdgcn_sched_barrier(0); \
  __builtin_amdgcn_s_barrier(); \
  __builtin_amdgcn_sched_barrier(0); } while (0)

// ---------------------------------------------------------------------------
// Prepass: xbf[i][b][k] = bf16(x[b][i][k]).
// ---------------------------------------------------------------------------
__global__ __launch_bounds__(256)
void xcvt_kernel(const float* __restrict__ x, __bf16* __restrict__ xbf)
{
  const int total = (B_SZ*NINST*D_IN) / 4;
  for (int v = blockIdx.x*256 + threadIdx.x; v < total; v += gridDim.x*256) {
    const int k4 = v & 255;
    const int i  = (v >> 8) & 3;
    const int b  = v >> 10;
    f32x4 f = ((const f32x4*)x)[v];
    bf16x4 h; h[0]=(__bf16)f.x; h[1]=(__bf16)f.y; h[2]=(__bf16)f.z; h[3]=(__bf16)f.w;
    ((bf16x4*)xbf)[((size_t)i*B_SZ + b)*256 + k4] = h;
  }
}

// ---------------------------------------------------------------------------
// Phase 1 (R9 exact, measured ~164 us): inner = mask * (xbf . A).
// ---------------------------------------------------------------------------
__global__ __launch_bounds__(256, 2)
void p1_kernel(const __bf16* __restrict__ xbf, const float* __restrict__ A,
               const int* __restrict__ mask, __bf16* __restrict__ inner)
{
  const int bid = blockIdx.x;
  const int L   = (bid & 7) * 64 + (bid >> 3);
  const int bt  = L & 3;
  const int mt  = (L >> 2) & 1;
  const int icg = L >> 3;
  const int ic0 = icg * 4;
  const int i   = ic0 >> 6;
  const int c0  = ic0 & 63;
  const int b0  = bt * 128;
  const int m0  = mt * 128;

  const int tid  = threadIdx.x;
  const int lane = tid & 63;
  const int wid  = tid >> 6;
  const int wr   = wid >> 1;
  const int wc   = wid & 1;

  __shared__ __align__(16) char smem[65536];
  __bf16* Xs = (__bf16*)smem;
  __bf16* As = (__bf16*)(smem + 32768);

  f32x4 acc[4][4];
#pragma unroll
  for (int a_ = 0; a_ < 4; ++a_)
#pragma unroll
    for (int b_ = 0; b_ < 4; ++b_)
      acc[a_][b_] = (f32x4){0.f, 0.f, 0.f, 0.f};

  const __bf16* xbase  = xbf + ((size_t)i * B_SZ + b0) * D_IN;
  const float*  Abase0 = A + (size_t)ic0 * D_IN * MRANK + m0;

  const int bo = tid & 127;
  const int bg = tid >> 7;
  float areg[4][8];

  auto stageXs = [&](int buf, int kt) {
#pragma unroll
    for (int q = 0; q < 4; ++q) {
      const int ci  = wid*4 + q;
      const int row = ci*8 + (lane >> 3);
      const int kch = (lane & 7) ^ (row & 7);
      gload16(xbase + (size_t)row * D_IN + (kt & 15)*64 + kch*8,
              Xs + buf*8192 + ci*512);
    }
  };
  auto loadA = [&](int kt) {
    const float* Ab = Abase0 + (size_t)(kt >> 4) * D_IN * MRANK;
#pragma unroll
    for (int q = 0; q < 4; ++q)
#pragma unroll
      for (int j = 0; j < 8; ++j)
        areg[q][j] = Ab[(size_t)((kt & 15)*64 + (bg*4+q)*8 + j)*MRANK + bo];
  };
  auto writeA = [&](int buf) {
#pragma unroll
    for (int q = 0; q < 4; ++q) {
      const int oct = bg*4 + q;
      bf16x8 h;
#pragma unroll
      for (int j = 0; j < 8; ++j) h[j] = (__bf16)areg[q][j];
      *(bf16x8*)(As + buf*8192 + bo*64 + ((oct ^ (bo & 7)))*8) = h;
    }
  };

  stageXs(0, 0); loadA(0); writeA(0);
  __syncthreads();

  int cur = 0;
  for (int kt = 0; kt < 64; ++kt) {
    if (kt+1 < 64) { stageXs(cur ^ 1, kt+1); loadA(kt+1); }
#pragma unroll
    for (int kk = 0; kk < 2; ++kk) {
      const int oct = kk*4 + (lane >> 4);
      bf16x8 af[4];
#pragma unroll
      for (int mi = 0; mi < 4; ++mi) {
        const int row = wr*64 + mi*16 + (lane & 15);
        af[mi] = *(const bf16x8*)(Xs + cur*8192 + row*64 + ((oct ^ (row & 7)))*8);
      }
#pragma unroll
      for (int ni = 0; ni < 4; ++ni) {
        const int col = wc*64 + ni*16 + (lane & 15);
        bf16x8 bfr = *(const bf16x8*)(As + cur*8192 + col*64 + ((oct ^ (col & 7)))*8);
#pragma unroll
        for (int mi = 0; mi < 4; ++mi)
          acc[mi][ni] = __builtin_amdgcn_mfma_f32_16x16x32_bf16(af[mi], bfr, acc[mi][ni], 0, 0, 0);
      }
    }
    if ((kt & 15) == 15) {
      const int c = c0 + (kt >> 4);
      __bf16* obase = inner + ((size_t)i * B_SZ + b0) * KTOT + (size_t)c * MRANK + m0;
      float mv[16];
#pragma unroll
      for (int mi = 0; mi < 4; ++mi)
#pragma unroll
        for (int j = 0; j < 4; ++j) {
          const int row = wr*64 + mi*16 + (lane >> 4)*4 + j;
          mv[mi*4+j] = (float)mask[(size_t)(b0 + row) * (NINST*CCOMP) + i*CCOMP + c];
        }
#pragma unroll
      for (int mi = 0; mi < 4; ++mi)
#pragma unroll
        for (int ni = 0; ni < 4; ++ni) {
          const int colL = wc*64 + ni*16 + (lane & 15);
#pragma unroll
          for (int j = 0; j < 4; ++j) {
            const int rowL = wr*64 + mi*16 + (lane >> 4)*4 + j;
            obase[(size_t)rowL * KTOT + colL] = (__bf16)(acc[mi][ni][j] * mv[mi*4+j]);
          }
#pragma unroll
          for (int j = 0; j < 4; ++j) acc[mi][ni][j] = 0.f;
        }
    }
    if (kt+1 < 64) writeA(cur ^ 1);
    __syncthreads();
    cur ^= 1;
  }
}

// ---------------------------------------------------------------------------
// Phase 2, 8-phase-style: 256x256 tile, BK=64, 512 thr = 8 waves (2M x 4N),
// per-wave 128x64 out (acc 8x4 f32x4).  As: 3 slots (DMA 2 steps ahead ->
// end-barrier vmcnt(4) keeps the prefetch in flight across the barrier, T4).
// Bs: 2 bufs, reg-staged fp32->bf16 (32 early loads, XOR ds_write).
// LDS = 5 x 32 KB = 160 KiB exactly, 1 block/CU.  ONE barrier per K-step.
// grid 32*nks (nks=8 -> 256 = 1/CU), K-slice = 16384/nks.
// ---------------------------------------------------------------------------
__global__ __launch_bounds__(512, 1)
void p2_kernel(const __bf16* __restrict__ inner, const float* __restrict__ Bm,
               float* __restrict__ dst, int nks)
{
  const int bid = blockIdx.x;
  const int nwg = gridDim.x;
  const int L   = (bid & 7) * (nwg >> 3) + (bid >> 3);
  const int tile = L & 7;
  const int rest = L >> 3;          // i*nks + ks
  const int ks  = rest % nks;
  const int i   = rest / nks;
  const int mt  = tile & 1;
  const int nt  = tile >> 1;
  const int b0  = mt * 256;
  const int o0  = nt * 256;
  const int NSTEP = (KTOT/64) / nks;
  const int kb0   = ks * NSTEP;

  const int tid  = threadIdx.x;
  const int lane = tid & 63;
  const int wid  = tid >> 6;        // 0..7
  const int wr   = wid >> 2;        // 0..1 : 128-row strip
  const int wc   = wid & 3;         // 0..3 : 64-col strip

  // As [3][256][64] bf16 (96 KB) + Bs [2][256][64] bf16 (64 KB) = 160 KiB.
  __shared__ __align__(16) char smem[163840];
  __bf16* As = (__bf16*)smem;
  __bf16* Bs = (__bf16*)(smem + 98304);

  f32x4 acc[8][4];
#pragma unroll
  for (int a_ = 0; a_ < 8; ++a_)
#pragma unroll
    for (int b_ = 0; b_ < 4; ++b_)
      acc[a_][b_] = (f32x4){0.f, 0.f, 0.f, 0.f};

  const __bf16* ibase = inner + ((size_t)i * B_SZ + b0) * KTOT;
  const float*  Bbase = Bm + (size_t)i * KTOT * D_OUTD + o0;

  const int bo = tid & 255;         // B column o (256)
  const int bg = tid >> 8;          // 0..1 -> octets bg*4..bg*4+3
  float breg[4][8];

  auto stageA = [&](int slot, int kt) {      // 256 rows x 64 k bf16, DMA
#pragma unroll
    for (int q = 0; q < 4; ++q) {
      const int u   = wid*4 + q;             // 0..31, wave-uniform
      const int row = u*8 + (lane >> 3);
      const int kch = (lane & 7) ^ (row & 7);
      gload16(ibase + (size_t)row * KTOT + (size_t)(kb0 + kt)*64 + kch*8,
              As + slot*16384 + u*512);
    }
  };
  auto loadB = [&](int kt) {
#pragma unroll
    for (int q = 0; q < 4; ++q)
#pragma unroll
      for (int j = 0; j < 8; ++j)
        breg[q][j] = Bbase[(size_t)((size_t)(kb0 + kt)*64 + (bg*4+q)*8 + j)*D_OUTD + bo];
  };
  auto writeB = [&](int buf) {
#pragma unroll
    for (int q = 0; q < 4; ++q) {
      const int oct = bg*4 + q;
      bf16x8 h;
#pragma unroll
      for (int j = 0; j < 8; ++j) h[j] = (__bf16)breg[q][j];
      *(bf16x8*)(Bs + buf*16384 + bo*64 + ((oct ^ (bo & 7)))*8) = h;
    }
  };

  // prologue
  stageA(0, 0);
  stageA(1, 1);
  loadB(0); writeB(0);
  BARN(0);

  for (int t = 0; t < NSTEP; ++t) {
    const int aslot = t % 3;
    const int bbuf  = t & 1;
    if (t+2 < NSTEP) stageA((t+2) % 3, t+2);   // in flight across this+next step
    if (t+1 < NSTEP) loadB(t+1);               // early issue; drained by writeB
    // ---- 4 phases: (kk, mh), 16 MFMA each ----
#pragma unroll
    for (int kk = 0; kk < 2; ++kk) {
      const int oct = kk*4 + (lane >> 4);
      bf16x8 bf[4];
#pragma unroll
      for (int ni = 0; ni < 4; ++ni) {
        const int col = wc*64 + ni*16 + (lane & 15);
        bf[ni] = *(const bf16x8*)(Bs + bbuf*16384 + col*64 + ((oct ^ (col & 7)))*8);
      }
#pragma unroll
      for (int mh = 0; mh < 2; ++mh) {
        bf16x8 af[4];
#pragma unroll
        for (int mi = 0; mi < 4; ++mi) {
          const int row = wr*128 + (mh*4 + mi)*16 + (lane & 15);
          af[mi] = *(const bf16x8*)(As + aslot*16384 + row*64 + ((oct ^ (row & 7)))*8);
        }
        __builtin_amdgcn_s_setprio(1);
#pragma unroll
        for (int ni = 0; ni < 4; ++ni)
#pragma unroll
          for (int mi = 0; mi < 4; ++mi)
            acc[mh*4+mi][ni] = __builtin_amdgcn_mfma_f32_16x16x32_bf16(
                af[mi], bf[ni], acc[mh*4+mi][ni], 0, 0, 0);
        __builtin_amdgcn_s_setprio(0);
      }
    }
    if (t+1 < NSTEP) writeB(bbuf ^ 1);         // waits its own loads only
    if (t+2 < NSTEP) BARN(4);                  // keep A(t+2) DMA in flight
    else             BARN(0);
  }

  // ---- epilogue: direct f32 stores ----
  float* obase = dst + (size_t)ks * ((size_t)B_SZ*NINST*D_OUTD)
               + ((size_t)b0 * NINST + i) * D_OUTD + o0;
#pragma unroll
  for (int mi = 0; mi < 8; ++mi)
#pragma unroll
    for (int ni = 0; ni < 4; ++ni) {
      const int colL = wc*64 + ni*16 + (lane & 15);
#pragma unroll
      for (int j = 0; j < 4; ++j) {
        const int rowL = wr*128 + mi*16 + (lane >> 4)*4 + j;
        obase[(size_t)rowL * (NINST*D_OUTD) + colL] = acc[mi][ni][j];
      }
    }
}

__global__ __launch_bounds__(256)
void reduce_kernel(const float* __restrict__ part, float* __restrict__ out, int nks)
{
  const int total = (B_SZ*NINST*D_OUTD) / 4;
  for (int v = blockIdx.x*256 + threadIdx.x; v < total; v += gridDim.x*256) {
    f32x4 s = ((const f32x4*)part)[v];
    for (int ks = 1; ks < nks; ++ks)
      s += ((const f32x4*)part)[(size_t)ks*total + v];
    ((f32x4*)out)[v] = s;
  }
}

extern "C" void kernel_launch(void* const* d_in, const int* in_sizes, int n_in,
                              void* d_out, int out_size, void* d_ws, size_t ws_size,
                              hipStream_t stream) {
  const float* x    = (const float*)d_in[0];
  const float* A    = (const float*)d_in[1];
  const float* Bm   = (const float*)d_in[2];
  const int*   mask = (const int*)d_in[3];

  const size_t innerB = (size_t)NINST * B_SZ * KTOT * 2;       // 64 MB
  const size_t xbfB   = (size_t)NINST * B_SZ * D_IN * 2;       // 4 MB
  const size_t partB  = (size_t)B_SZ * NINST * D_OUTD * 4;     // 8 MB per split

  char* p = (char*)d_ws;
  __bf16* inner = (__bf16*)p;             p += innerB;
  __bf16* xbf   = (__bf16*)p;             p += xbfB;
  const size_t used = (size_t)(p - (char*)d_ws);

  int nks = 1;
  if      (ws_size >= used + 8*partB) nks = 8;
  else if (ws_size >= used + 4*partB) nks = 4;
  else if (ws_size >= used + 2*partB) nks = 2;
  float* part = (nks > 1) ? (float*)p : (float*)d_out;

  xcvt_kernel<<<dim3(1024),  dim3(256), 0, stream>>>(x, xbf);
  p1_kernel<<<dim3(512),     dim3(256), 0, stream>>>(xbf, A, mask, inner);
  p2_kernel<<<dim3(32*nks),  dim3(512), 0, stream>>>(inner, Bm, part, nks);
  if (nks > 1)
    reduce_kernel<<<dim3(1024), dim3(256), 0, stream>>>(part, (float*)d_out, nks);
}